// Round 1
// 4082.853 us; speedup vs baseline: 1.0040x; 1.0040x over previous
//
#include <hip/hip_runtime.h>

__device__ __forceinline__ float lrelu01(float v){ return v > 0.f ? v : 0.01f*v; }
__device__ __forceinline__ float lrelu2 (float v){ return v > 0.f ? v : 0.2f *v; }

// ---------------- zero int array ----------------
__global__ void k_zero(int* __restrict__ p, int n){
    int i = blockIdx.x*256 + threadIdx.x;
    if (i < n) p[i] = 0;
}

// ---------------- K1: feature MLP (des or tweet; optionally num/cat) -------
// computes lrelu(row @ W.T + b) -> x0[:, out_off:out_off+32]
__global__ __launch_bounds__(256) void k_feat(
    const float* __restrict__ rows, const float* __restrict__ W, const float* __restrict__ b,
    int out_off,
    const float* __restrict__ nump, const float* __restrict__ catp,
    const float* __restrict__ Wn, const float* __restrict__ bn,
    const float* __restrict__ Wc, const float* __restrict__ bc,
    int do_nc, float* __restrict__ x0, int N)
{
    int n = blockIdx.x*256 + threadIdx.x;
    if (n >= N) return;
    const float* xr = rows + (size_t)n*768;
    float acc[32];
    #pragma unroll
    for (int o=0;o<32;o++) acc[o]=0.f;
    for (int kc=0; kc<768; kc+=32){
        float xv[32];
        #pragma unroll
        for (int i=0;i<8;i++){
            float4 v = *(const float4*)(xr + kc + i*4);
            xv[i*4+0]=v.x; xv[i*4+1]=v.y; xv[i*4+2]=v.z; xv[i*4+3]=v.w;
        }
        #pragma unroll
        for (int o=0;o<32;o++){
            const float* wr = W + (size_t)o*768 + kc;
            #pragma unroll
            for (int kk=0;kk<32;kk++) acc[o] = fmaf(xv[kk], wr[kk], acc[o]);
        }
    }
    float* dst = x0 + (size_t)n*128 + out_off;
    #pragma unroll
    for (int o=0;o<32;o++) dst[o] = lrelu01(acc[o] + b[o]);

    if (do_nc){
        float xn[5], xc[3];
        #pragma unroll
        for (int i=0;i<5;i++) xn[i] = nump[(size_t)n*5+i];
        #pragma unroll
        for (int i=0;i<3;i++) xc[i] = catp[(size_t)n*3+i];
        float* d2 = x0 + (size_t)n*128 + 64;
        #pragma unroll
        for (int o=0;o<32;o++){
            float a = bn[o];
            #pragma unroll
            for (int k=0;k<5;k++) a = fmaf(xn[k], Wn[o*5+k], a);
            d2[o] = lrelu01(a);
        }
        float* d3 = x0 + (size_t)n*128 + 96;
        #pragma unroll
        for (int o=0;o<32;o++){
            float a = bc[o];
            #pragma unroll
            for (int k=0;k<3;k++) a = fmaf(xc[k], Wc[o*3+k], a);
            d3[o] = lrelu01(a);
        }
    }
}

// ---------------- K2: x1 = lrelu(Wi@x0+bi); xw1 = g1W@x1; e_src/e_dst/den_init
// Cooperative version: 512 threads per 128-node tile.
// thread (j = tid&127, oc = tid>>7): phase1 computes x1 rows oc*32..oc*32+31
// for node j into LDS; phase2 computes head h=oc of xw1 for node j.
// Same 64 KiB LDS now serves 512 threads -> 2 blocks/CU = 4 waves/SIMD
// (was 1 wave/SIMD with 128-thread blocks; Occupancy 9.7%, VALUBusy 5.7%).
__global__ __launch_bounds__(512, 4) void k_x1_xw1(
    const float* __restrict__ x0, const float* __restrict__ Wi, const float* __restrict__ bi,
    const float* __restrict__ g1W, const float* __restrict__ g1as, const float* __restrict__ g1ad,
    float* __restrict__ xw1, float* __restrict__ es1, float* __restrict__ ed1,
    float* __restrict__ den1, int N)
{
    __shared__ float x1s[128*128];   // layout [k][j] -> lanes (consecutive j) conflict-free
    int tid = threadIdx.x;
    int j   = tid & 127;             // node within tile
    int oc  = tid >> 7;              // output chunk (phase1) / head (phase2)
    int n   = blockIdx.x*128 + j;
    bool valid = (n < N);

    // ---- phase 1: x1[oc*32+o][j] = lrelu(x0[n] . Wi[oc*32+o] + bi) ----
    float acc[32];
    #pragma unroll
    for (int o=0;o<32;o++) acc[o]=0.f;
    if (valid){
        const float* xr = x0 + (size_t)n*128;
        for (int kc=0; kc<128; kc+=32){
            float xv[32];
            #pragma unroll
            for (int i=0;i<8;i++){
                float4 v = *(const float4*)(xr + kc + i*4);
                xv[i*4+0]=v.x; xv[i*4+1]=v.y; xv[i*4+2]=v.z; xv[i*4+3]=v.w;
            }
            #pragma unroll
            for (int o=0;o<32;o++){
                const float* wr = Wi + (size_t)(oc*32+o)*128 + kc;
                #pragma unroll
                for (int kk=0;kk<32;kk++) acc[o] = fmaf(xv[kk], wr[kk], acc[o]);
            }
        }
    }
    #pragma unroll
    for (int o=0;o<32;o++)
        x1s[(oc*32+o)*128 + j] = lrelu01(acc[o] + bi[oc*32+o]);
    __syncthreads();

    // ---- phase 2: head h = oc; xw1[n][h*32..] = x1[n] @ g1W[h]^T ----
    int h = oc;
    #pragma unroll
    for (int o=0;o<32;o++) acc[o]=0.f;
    for (int kc=0; kc<128; kc+=32){
        float xv[32];
        #pragma unroll
        for (int kk=0;kk<32;kk++) xv[kk] = x1s[(kc+kk)*128 + j];
        #pragma unroll
        for (int o=0;o<32;o++){
            const float* wr = g1W + (size_t)(h*32+o)*128 + kc;
            #pragma unroll
            for (int kk=0;kk<32;kk++) acc[o] = fmaf(xv[kk], wr[kk], acc[o]);
        }
    }
    if (valid){
        float es=0.f, ed=0.f;
        #pragma unroll
        for (int d=0; d<32; d++){
            es = fmaf(acc[d], g1as[h*32+d], es);
            ed = fmaf(acc[d], g1ad[h*32+d], ed);
        }
        float* xo = xw1 + (size_t)n*128 + h*32;
        #pragma unroll
        for (int i=0;i<8;i++){
            float4 v; v.x=acc[i*4]; v.y=acc[i*4+1]; v.z=acc[i*4+2]; v.w=acc[i*4+3];
            *(float4*)(xo + i*4) = v;
        }
        es1[n*4+h] = es; ed1[n*4+h] = ed;
        den1[n*4+h] = __expf(lrelu2(es+ed));   // self-loop term seeds den
    }
}

// ---------------- CSR build ----------------
__global__ void k_hist(const int* __restrict__ ei, int E, int* __restrict__ counts){
    int e = blockIdx.x*256 + threadIdx.x;
    if (e >= E) return;
    atomicAdd(&counts[ei[E+e]], 1);
}

#define SCAN_BS 1024
__global__ __launch_bounds__(256) void k_scan1(const int* __restrict__ counts,
        int* __restrict__ excl, int* __restrict__ bsums, int n){
    __shared__ int s[256];
    int t = threadIdx.x, b = blockIdx.x;
    int base = b*SCAN_BS + t*4;
    int v[4]; int tot = 0;
    #pragma unroll
    for (int i=0;i<4;i++){ v[i] = (base+i < n) ? counts[base+i] : 0; tot += v[i]; }
    s[t] = tot; __syncthreads();
    for (int off=1; off<256; off<<=1){
        int x = (t>=off) ? s[t-off] : 0;
        __syncthreads();
        s[t] += x;
        __syncthreads();
    }
    int ex = s[t] - tot;
    if (t == 255) bsums[b] = s[255];
    int r = ex;
    #pragma unroll
    for (int i=0;i<4;i++){ if (base+i < n) excl[base+i] = r; r += v[i]; }
}

__global__ __launch_bounds__(256) void k_scan2(int* __restrict__ bsums, int nb){
    __shared__ int s[256];
    int t = threadIdx.x;
    int v = (t < nb) ? bsums[t] : 0;
    s[t] = v; __syncthreads();
    for (int off=1; off<256; off<<=1){
        int x = (t>=off) ? s[t-off] : 0;
        __syncthreads();
        s[t] += x;
        __syncthreads();
    }
    if (t < nb) bsums[t] = s[t] - v;
}

__global__ void k_scan3(const int* __restrict__ excl, const int* __restrict__ bsums,
        int* __restrict__ indptr, int* __restrict__ cursor, int n, int E){
    int i = blockIdx.x*256 + threadIdx.x;
    if (i < n){ int v = excl[i] + bsums[i/SCAN_BS]; indptr[i] = v; cursor[i] = v; }
    if (i == 0) indptr[n] = E;
}

__global__ void k_scatter(const int* __restrict__ ei, int E,
        int* __restrict__ cursor, int* __restrict__ srcs){
    int e = blockIdx.x*256 + threadIdx.x;
    if (e >= E) return;
    int d = ei[E+e];
    int p = atomicAdd(&cursor[d], 1);
    srcs[p] = ei[e];
}

// ---------------- denominators (edge-parallel atomics) ----------------
__global__ void k_den1(const int* __restrict__ ei, int E,
        const float* __restrict__ es1, const float* __restrict__ ed1, float* __restrict__ den1){
    int e = blockIdx.x*256 + threadIdx.x;
    if (e >= E) return;
    int s = ei[e], d = ei[E+e];
    #pragma unroll
    for (int h=0; h<4; h++){
        float v = es1[s*4+h] + ed1[d*4+h];
        atomicAdd(&den1[d*4+h], __expf(lrelu2(v)));
    }
}

__global__ void k_den2(const int* __restrict__ ei, int E,
        const float* __restrict__ es2, const float* __restrict__ ed2, float* __restrict__ den2){
    int e = blockIdx.x*256 + threadIdx.x;
    if (e >= E) return;
    int s = ei[e], d = ei[E+e];
    float v = es2[s] + ed2[d];
    atomicAdd(&den2[d], __expf(lrelu2(v)));
}

// ---------------- GAT aggregation (one block per dst node) ----------------
__global__ __launch_bounds__(128) void k_agg1(
    const int* __restrict__ indptr, const int* __restrict__ srcs,
    const float* __restrict__ xw1, const float* __restrict__ es1, const float* __restrict__ ed1,
    const float* __restrict__ den1, const float* __restrict__ g1b, float* __restrict__ x2)
{
    int n = blockIdx.x;
    int col = threadIdx.x;
    int h = col >> 5;
    float edn = ed1[n*4+h];
    float invden = 1.0f / den1[n*4+h];
    float eself = lrelu2(es1[n*4+h] + edn);
    float acc = __expf(eself) * invden * xw1[(size_t)n*128 + col];
    int i0 = indptr[n], i1 = indptr[n+1];
    for (int i=i0; i<i1; i++){
        int s = srcs[i];
        float e = lrelu2(es1[s*4+h] + edn);
        acc = fmaf(__expf(e) * invden, xw1[(size_t)s*128 + col], acc);
    }
    x2[(size_t)n*128 + col] = acc + g1b[col];
}

__global__ __launch_bounds__(128) void k_agg2(
    const int* __restrict__ indptr, const int* __restrict__ srcs,
    const float* __restrict__ xw2, const float* __restrict__ es2, const float* __restrict__ ed2,
    const float* __restrict__ den2, const float* __restrict__ g2b, float* __restrict__ x3)
{
    int n = blockIdx.x;
    int col = threadIdx.x;
    float edn = ed2[n];
    float invden = 1.0f / den2[n];
    float eself = lrelu2(es2[n] + edn);
    float acc = __expf(eself) * invden * xw2[(size_t)n*128 + col];
    int i0 = indptr[n], i1 = indptr[n+1];
    for (int i=i0; i<i1; i++){
        int s = srcs[i];
        float e = lrelu2(es2[s] + edn);
        acc = fmaf(__expf(e) * invden, xw2[(size_t)s*128 + col], acc);
    }
    x3[(size_t)n*128 + col] = acc + g2b[col];
}

// ---------------- K6: xw2 = g2W @ x2 ; e_src2/e_dst2/den2_init ----------------
__global__ __launch_bounds__(256) void k_xw2(
    const float* __restrict__ x2, const float* __restrict__ g2W,
    const float* __restrict__ g2as, const float* __restrict__ g2ad,
    float* __restrict__ xw2, float* __restrict__ es2, float* __restrict__ ed2,
    float* __restrict__ den2, int N)
{
    int n = blockIdx.x*256 + threadIdx.x;
    if (n >= N) return;
    const float* xr = x2 + (size_t)n*128;
    float es=0.f, ed=0.f;
    for (int oc=0; oc<4; oc++){
        float acc[32];
        #pragma unroll
        for (int o=0;o<32;o++) acc[o]=0.f;
        for (int kc=0; kc<128; kc+=32){
            float xv[32];
            #pragma unroll
            for (int i=0;i<8;i++){
                float4 v = *(const float4*)(xr + kc + i*4);
                xv[i*4+0]=v.x; xv[i*4+1]=v.y; xv[i*4+2]=v.z; xv[i*4+3]=v.w;
            }
            #pragma unroll
            for (int o=0;o<32;o++){
                const float* wr = g2W + (size_t)(oc*32+o)*128 + kc;
                #pragma unroll
                for (int kk=0;kk<32;kk++) acc[o] = fmaf(xv[kk], wr[kk], acc[o]);
            }
        }
        float* xo = xw2 + (size_t)n*128 + oc*32;
        #pragma unroll
        for (int i=0;i<8;i++){
            float4 v; v.x=acc[i*4]; v.y=acc[i*4+1]; v.z=acc[i*4+2]; v.w=acc[i*4+3];
            *(float4*)(xo + i*4) = v;
        }
        #pragma unroll
        for (int d=0; d<32; d++){
            es = fmaf(acc[d], g2as[oc*32+d], es);
            ed = fmaf(acc[d], g2ad[oc*32+d], ed);
        }
    }
    es2[n] = es; ed2[n] = ed;
    den2[n] = __expf(lrelu2(es+ed));
}

// ---------------- K9: out = lrelu(x3@Wo1.T+bo1) @ Wo2.T + bo2 ----------------
__global__ __launch_bounds__(256) void k_head(
    const float* __restrict__ x3, const float* __restrict__ Wo1, const float* __restrict__ bo1,
    const float* __restrict__ Wo2, const float* __restrict__ bo2,
    float* __restrict__ out, int N)
{
    int n = blockIdx.x*256 + threadIdx.x;
    if (n >= N) return;
    const float* xr = x3 + (size_t)n*128;
    float o0 = bo2[0], o1 = bo2[1];
    for (int oc=0; oc<4; oc++){
        float acc[32];
        #pragma unroll
        for (int o=0;o<32;o++) acc[o] = bo1[oc*32+o];
        for (int kc=0; kc<128; kc+=32){
            float xv[32];
            #pragma unroll
            for (int i=0;i<8;i++){
                float4 v = *(const float4*)(xr + kc + i*4);
                xv[i*4+0]=v.x; xv[i*4+1]=v.y; xv[i*4+2]=v.z; xv[i*4+3]=v.w;
            }
            #pragma unroll
            for (int o=0;o<32;o++){
                const float* wr = Wo1 + (size_t)(oc*32+o)*128 + kc;
                #pragma unroll
                for (int kk=0;kk<32;kk++) acc[o] = fmaf(xv[kk], wr[kk], acc[o]);
            }
        }
        #pragma unroll
        for (int o=0;o<32;o++){
            float v = lrelu01(acc[o]);
            o0 = fmaf(v, Wo2[oc*32+o],       o0);
            o1 = fmaf(v, Wo2[128 + oc*32+o], o1);
        }
    }
    out[(size_t)n*2+0] = o0;
    out[(size_t)n*2+1] = o1;
}

extern "C" void kernel_launch(void* const* d_in, const int* in_sizes, int n_in,
                              void* d_out, int out_size, void* d_ws, size_t ws_size,
                              hipStream_t stream)
{
    const float* des  = (const float*)d_in[0];
    const float* twt  = (const float*)d_in[1];
    const float* nump = (const float*)d_in[2];
    const float* catp = (const float*)d_in[3];
    const int*   ei   = (const int*)  d_in[4];
    const float* Wd = (const float*)d_in[5];   const float* bd = (const float*)d_in[6];
    const float* Wt = (const float*)d_in[7];   const float* bt = (const float*)d_in[8];
    const float* Wn = (const float*)d_in[9];   const float* bn = (const float*)d_in[10];
    const float* Wc = (const float*)d_in[11];  const float* bc = (const float*)d_in[12];
    const float* Wi = (const float*)d_in[13];  const float* bi = (const float*)d_in[14];
    const float* g1W  = (const float*)d_in[15];
    const float* g1as = (const float*)d_in[16];
    const float* g1ad = (const float*)d_in[17];
    const float* g1b  = (const float*)d_in[18];
    const float* g2W  = (const float*)d_in[19];
    const float* g2as = (const float*)d_in[20];
    const float* g2ad = (const float*)d_in[21];
    const float* g2b  = (const float*)d_in[22];
    const float* Wo1 = (const float*)d_in[23]; const float* bo1 = (const float*)d_in[24];
    const float* Wo2 = (const float*)d_in[25]; const float* bo2 = (const float*)d_in[26];
    float* out = (float*)d_out;

    const int N = in_sizes[0] / 768;
    const int E = in_sizes[4] / 2;

    float* b0   = (float*)d_ws;                 // x0 -> x2 -> x3
    float* b1   = b0   + (size_t)N*128;         // xw1 -> xw2
    float* es1  = b1   + (size_t)N*128;
    float* ed1  = es1  + (size_t)N*4;
    float* den1 = ed1  + (size_t)N*4;
    float* es2  = den1 + (size_t)N*4;
    float* ed2  = es2  + N;
    float* den2 = ed2  + N;
    int* counts = (int*)(den2 + N);
    int* excl   = counts + N;
    int* bsums  = excl   + N;
    int* indptr = bsums  + 256;
    int* cursor = indptr + (N+1);
    int* srcs   = cursor + N;

    const int gN256 = (N+255)/256;
    const int gE256 = (E+255)/256;
    const int gN128 = (N+127)/128;
    const int nb    = (N + SCAN_BS - 1)/SCAN_BS;

    hipLaunchKernelGGL(k_zero,   dim3(gN256), dim3(256), 0, stream, counts, N);
    hipLaunchKernelGGL(k_feat,   dim3(gN256), dim3(256), 0, stream,
                       des, Wd, bd, 0,  nump, catp, Wn, bn, Wc, bc, 1, b0, N);
    hipLaunchKernelGGL(k_feat,   dim3(gN256), dim3(256), 0, stream,
                       twt, Wt, bt, 32, nump, catp, Wn, bn, Wc, bc, 0, b0, N);
    hipLaunchKernelGGL(k_x1_xw1, dim3(gN128), dim3(512), 0, stream,
                       b0, Wi, bi, g1W, g1as, g1ad, b1, es1, ed1, den1, N);
    hipLaunchKernelGGL(k_hist,   dim3(gE256), dim3(256), 0, stream, ei, E, counts);
    hipLaunchKernelGGL(k_scan1,  dim3(nb),    dim3(256), 0, stream, counts, excl, bsums, N);
    hipLaunchKernelGGL(k_scan2,  dim3(1),     dim3(256), 0, stream, bsums, nb);
    hipLaunchKernelGGL(k_scan3,  dim3(gN256), dim3(256), 0, stream, excl, bsums, indptr, cursor, N, E);
    hipLaunchKernelGGL(k_scatter,dim3(gE256), dim3(256), 0, stream, ei, E, cursor, srcs);
    hipLaunchKernelGGL(k_den1,   dim3(gE256), dim3(256), 0, stream, ei, E, es1, ed1, den1);
    hipLaunchKernelGGL(k_agg1,   dim3(N),     dim3(128), 0, stream,
                       indptr, srcs, b1, es1, ed1, den1, g1b, b0);
    hipLaunchKernelGGL(k_xw2,    dim3(gN256), dim3(256), 0, stream,
                       b0, g2W, g2as, g2ad, b1, es2, ed2, den2, N);
    hipLaunchKernelGGL(k_den2,   dim3(gE256), dim3(256), 0, stream, ei, E, es2, ed2, den2);
    hipLaunchKernelGGL(k_agg2,   dim3(N),     dim3(128), 0, stream,
                       indptr, srcs, b1, es2, ed2, den2, g2b, b0);
    hipLaunchKernelGGL(k_head,   dim3(gN256), dim3(256), 0, stream,
                       b0, Wo1, bo1, Wo2, bo2, out, N);
}

// Round 2
// 3472.168 us; speedup vs baseline: 1.1806x; 1.1759x over previous
//
#include <hip/hip_runtime.h>

__device__ __forceinline__ float lrelu01(float v){ return v > 0.f ? v : 0.01f*v; }
__device__ __forceinline__ float lrelu2 (float v){ return v > 0.f ? v : 0.2f *v; }

// ---------------- zero int array ----------------
__global__ void k_zero(int* __restrict__ p, int n){
    int i = blockIdx.x*256 + threadIdx.x;
    if (i < n) p[i] = 0;
}

// ---------------- K1: feature MLP (des or tweet; optionally num/cat) -------
// computes lrelu(row @ W.T + b) -> x0[:, out_off:out_off+32]
// amdgpu_waves_per_eu(4,4): pin 4 waves/SIMD -> 128-VGPR budget so the
// acc[32]+xv[32] register tile stays in VGPRs (default heuristic gave 36
// VGPRs -> reload/spill, 668 us at 15% VALUBusy).
__global__ __launch_bounds__(256) __attribute__((amdgpu_waves_per_eu(4,4))) void k_feat(
    const float* __restrict__ rows, const float* __restrict__ W, const float* __restrict__ b,
    int out_off,
    const float* __restrict__ nump, const float* __restrict__ catp,
    const float* __restrict__ Wn, const float* __restrict__ bn,
    const float* __restrict__ Wc, const float* __restrict__ bc,
    int do_nc, float* __restrict__ x0, int N)
{
    int n = blockIdx.x*256 + threadIdx.x;
    if (n >= N) return;
    const float* xr = rows + (size_t)n*768;
    float acc[32];
    #pragma unroll
    for (int o=0;o<32;o++) acc[o]=0.f;
    for (int kc=0; kc<768; kc+=32){
        float xv[32];
        #pragma unroll
        for (int i=0;i<8;i++){
            float4 v = *(const float4*)(xr + kc + i*4);
            xv[i*4+0]=v.x; xv[i*4+1]=v.y; xv[i*4+2]=v.z; xv[i*4+3]=v.w;
        }
        #pragma unroll
        for (int o=0;o<32;o++){
            const float* wr = W + (size_t)o*768 + kc;
            #pragma unroll
            for (int kk=0;kk<32;kk++) acc[o] = fmaf(xv[kk], wr[kk], acc[o]);
        }
    }
    float* dst = x0 + (size_t)n*128 + out_off;
    #pragma unroll
    for (int o=0;o<32;o++) dst[o] = lrelu01(acc[o] + b[o]);

    if (do_nc){
        float xn[5], xc[3];
        #pragma unroll
        for (int i=0;i<5;i++) xn[i] = nump[(size_t)n*5+i];
        #pragma unroll
        for (int i=0;i<3;i++) xc[i] = catp[(size_t)n*3+i];
        float* d2 = x0 + (size_t)n*128 + 64;
        #pragma unroll
        for (int o=0;o<32;o++){
            float a = bn[o];
            #pragma unroll
            for (int k=0;k<5;k++) a = fmaf(xn[k], Wn[o*5+k], a);
            d2[o] = lrelu01(a);
        }
        float* d3 = x0 + (size_t)n*128 + 96;
        #pragma unroll
        for (int o=0;o<32;o++){
            float a = bc[o];
            #pragma unroll
            for (int k=0;k<3;k++) a = fmaf(xc[k], Wc[o*3+k], a);
            d3[o] = lrelu01(a);
        }
    }
}

// ---------------- K2: x1 = lrelu(Wi@x0+bi); xw1 = g1W@x1; e_src/e_dst/den_init
// Cooperative: 512 threads per 128-node tile; LDS 64KB caps us at 2 blocks/CU
// = 4 waves/SIMD. amdgpu_waves_per_eu(4,4) pins the allocator there (128-VGPR
// budget) — round-1's launch_bounds(512,4) let it chase 8 waves/SIMD at 64
// VGPRs, spilling acc[32]+xv[32] to scratch (WRITE_SIZE 352 MB vs 56 MB real).
__global__ __launch_bounds__(512) __attribute__((amdgpu_waves_per_eu(4,4))) void k_x1_xw1(
    const float* __restrict__ x0, const float* __restrict__ Wi, const float* __restrict__ bi,
    const float* __restrict__ g1W, const float* __restrict__ g1as, const float* __restrict__ g1ad,
    float* __restrict__ xw1, float* __restrict__ es1, float* __restrict__ ed1,
    float* __restrict__ den1, int N)
{
    __shared__ float x1s[128*128];   // layout [k][j] -> lanes (consecutive j) conflict-free
    int tid = threadIdx.x;
    int j   = tid & 127;             // node within tile
    int oc  = tid >> 7;              // output chunk (phase1) / head (phase2)
    int n   = blockIdx.x*128 + j;
    bool valid = (n < N);

    // ---- phase 1: x1[oc*32+o][j] = lrelu(x0[n] . Wi[oc*32+o] + bi) ----
    float acc[32];
    #pragma unroll
    for (int o=0;o<32;o++) acc[o]=0.f;
    if (valid){
        const float* xr = x0 + (size_t)n*128;
        for (int kc=0; kc<128; kc+=32){
            float xv[32];
            #pragma unroll
            for (int i=0;i<8;i++){
                float4 v = *(const float4*)(xr + kc + i*4);
                xv[i*4+0]=v.x; xv[i*4+1]=v.y; xv[i*4+2]=v.z; xv[i*4+3]=v.w;
            }
            #pragma unroll
            for (int o=0;o<32;o++){
                const float* wr = Wi + (size_t)(oc*32+o)*128 + kc;
                #pragma unroll
                for (int kk=0;kk<32;kk++) acc[o] = fmaf(xv[kk], wr[kk], acc[o]);
            }
        }
    }
    #pragma unroll
    for (int o=0;o<32;o++)
        x1s[(oc*32+o)*128 + j] = lrelu01(acc[o] + bi[oc*32+o]);
    __syncthreads();

    // ---- phase 2: head h = oc; xw1[n][h*32..] = x1[n] @ g1W[h]^T ----
    int h = oc;
    #pragma unroll
    for (int o=0;o<32;o++) acc[o]=0.f;
    for (int kc=0; kc<128; kc+=32){
        float xv[32];
        #pragma unroll
        for (int kk=0;kk<32;kk++) xv[kk] = x1s[(kc+kk)*128 + j];
        #pragma unroll
        for (int o=0;o<32;o++){
            const float* wr = g1W + (size_t)(h*32+o)*128 + kc;
            #pragma unroll
            for (int kk=0;kk<32;kk++) acc[o] = fmaf(xv[kk], wr[kk], acc[o]);
        }
    }
    if (valid){
        float es=0.f, ed=0.f;
        #pragma unroll
        for (int d=0; d<32; d++){
            es = fmaf(acc[d], g1as[h*32+d], es);
            ed = fmaf(acc[d], g1ad[h*32+d], ed);
        }
        float* xo = xw1 + (size_t)n*128 + h*32;
        #pragma unroll
        for (int i=0;i<8;i++){
            float4 v; v.x=acc[i*4]; v.y=acc[i*4+1]; v.z=acc[i*4+2]; v.w=acc[i*4+3];
            *(float4*)(xo + i*4) = v;
        }
        es1[n*4+h] = es; ed1[n*4+h] = ed;
        den1[n*4+h] = __expf(lrelu2(es+ed));   // self-loop term seeds den
    }
}

// ---------------- CSR build ----------------
__global__ void k_hist(const int* __restrict__ ei, int E, int* __restrict__ counts){
    int e = blockIdx.x*256 + threadIdx.x;
    if (e >= E) return;
    atomicAdd(&counts[ei[E+e]], 1);
}

#define SCAN_BS 1024
__global__ __launch_bounds__(256) void k_scan1(const int* __restrict__ counts,
        int* __restrict__ excl, int* __restrict__ bsums, int n){
    __shared__ int s[256];
    int t = threadIdx.x, b = blockIdx.x;
    int base = b*SCAN_BS + t*4;
    int v[4]; int tot = 0;
    #pragma unroll
    for (int i=0;i<4;i++){ v[i] = (base+i < n) ? counts[base+i] : 0; tot += v[i]; }
    s[t] = tot; __syncthreads();
    for (int off=1; off<256; off<<=1){
        int x = (t>=off) ? s[t-off] : 0;
        __syncthreads();
        s[t] += x;
        __syncthreads();
    }
    int ex = s[t] - tot;
    if (t == 255) bsums[b] = s[255];
    int r = ex;
    #pragma unroll
    for (int i=0;i<4;i++){ if (base+i < n) excl[base+i] = r; r += v[i]; }
}

__global__ __launch_bounds__(256) void k_scan2(int* __restrict__ bsums, int nb){
    __shared__ int s[256];
    int t = threadIdx.x;
    int v = (t < nb) ? bsums[t] : 0;
    s[t] = v; __syncthreads();
    for (int off=1; off<256; off<<=1){
        int x = (t>=off) ? s[t-off] : 0;
        __syncthreads();
        s[t] += x;
        __syncthreads();
    }
    if (t < nb) bsums[t] = s[t] - v;
}

__global__ void k_scan3(const int* __restrict__ excl, const int* __restrict__ bsums,
        int* __restrict__ indptr, int* __restrict__ cursor, int n, int E){
    int i = blockIdx.x*256 + threadIdx.x;
    if (i < n){ int v = excl[i] + bsums[i/SCAN_BS]; indptr[i] = v; cursor[i] = v; }
    if (i == 0) indptr[n] = E;
}

__global__ void k_scatter(const int* __restrict__ ei, int E,
        int* __restrict__ cursor, int* __restrict__ srcs){
    int e = blockIdx.x*256 + threadIdx.x;
    if (e >= E) return;
    int d = ei[E+e];
    int p = atomicAdd(&cursor[d], 1);
    srcs[p] = ei[e];
}

// ---------------- denominators (edge-parallel atomics) ----------------
__global__ void k_den1(const int* __restrict__ ei, int E,
        const float* __restrict__ es1, const float* __restrict__ ed1, float* __restrict__ den1){
    int e = blockIdx.x*256 + threadIdx.x;
    if (e >= E) return;
    int s = ei[e], d = ei[E+e];
    #pragma unroll
    for (int h=0; h<4; h++){
        float v = es1[s*4+h] + ed1[d*4+h];
        atomicAdd(&den1[d*4+h], __expf(lrelu2(v)));
    }
}

__global__ void k_den2(const int* __restrict__ ei, int E,
        const float* __restrict__ es2, const float* __restrict__ ed2, float* __restrict__ den2){
    int e = blockIdx.x*256 + threadIdx.x;
    if (e >= E) return;
    int s = ei[e], d = ei[E+e];
    float v = es2[s] + ed2[d];
    atomicAdd(&den2[d], __expf(lrelu2(v)));
}

// ---------------- GAT aggregation (one block per dst node) ----------------
__global__ __launch_bounds__(128) void k_agg1(
    const int* __restrict__ indptr, const int* __restrict__ srcs,
    const float* __restrict__ xw1, const float* __restrict__ es1, const float* __restrict__ ed1,
    const float* __restrict__ den1, const float* __restrict__ g1b, float* __restrict__ x2)
{
    int n = blockIdx.x;
    int col = threadIdx.x;
    int h = col >> 5;
    float edn = ed1[n*4+h];
    float invden = 1.0f / den1[n*4+h];
    float eself = lrelu2(es1[n*4+h] + edn);
    float acc = __expf(eself) * invden * xw1[(size_t)n*128 + col];
    int i0 = indptr[n], i1 = indptr[n+1];
    for (int i=i0; i<i1; i++){
        int s = srcs[i];
        float e = lrelu2(es1[s*4+h] + edn);
        acc = fmaf(__expf(e) * invden, xw1[(size_t)s*128 + col], acc);
    }
    x2[(size_t)n*128 + col] = acc + g1b[col];
}

__global__ __launch_bounds__(128) void k_agg2(
    const int* __restrict__ indptr, const int* __restrict__ srcs,
    const float* __restrict__ xw2, const float* __restrict__ es2, const float* __restrict__ ed2,
    const float* __restrict__ den2, const float* __restrict__ g2b, float* __restrict__ x3)
{
    int n = blockIdx.x;
    int col = threadIdx.x;
    float edn = ed2[n];
    float invden = 1.0f / den2[n];
    float eself = lrelu2(es2[n] + edn);
    float acc = __expf(eself) * invden * xw2[(size_t)n*128 + col];
    int i0 = indptr[n], i1 = indptr[n+1];
    for (int i=i0; i<i1; i++){
        int s = srcs[i];
        float e = lrelu2(es2[s] + edn);
        acc = fmaf(__expf(e) * invden, xw2[(size_t)s*128 + col], acc);
    }
    x3[(size_t)n*128 + col] = acc + g2b[col];
}

// ---------------- K6: xw2 = g2W @ x2 ; e_src2/e_dst2/den2_init ----------------
__global__ __launch_bounds__(256) __attribute__((amdgpu_waves_per_eu(4,4))) void k_xw2(
    const float* __restrict__ x2, const float* __restrict__ g2W,
    const float* __restrict__ g2as, const float* __restrict__ g2ad,
    float* __restrict__ xw2, float* __restrict__ es2, float* __restrict__ ed2,
    float* __restrict__ den2, int N)
{
    int n = blockIdx.x*256 + threadIdx.x;
    if (n >= N) return;
    const float* xr = x2 + (size_t)n*128;
    float es=0.f, ed=0.f;
    for (int oc=0; oc<4; oc++){
        float acc[32];
        #pragma unroll
        for (int o=0;o<32;o++) acc[o]=0.f;
        for (int kc=0; kc<128; kc+=32){
            float xv[32];
            #pragma unroll
            for (int i=0;i<8;i++){
                float4 v = *(const float4*)(xr + kc + i*4);
                xv[i*4+0]=v.x; xv[i*4+1]=v.y; xv[i*4+2]=v.z; xv[i*4+3]=v.w;
            }
            #pragma unroll
            for (int o=0;o<32;o++){
                const float* wr = g2W + (size_t)(oc*32+o)*128 + kc;
                #pragma unroll
                for (int kk=0;kk<32;kk++) acc[o] = fmaf(xv[kk], wr[kk], acc[o]);
            }
        }
        float* xo = xw2 + (size_t)n*128 + oc*32;
        #pragma unroll
        for (int i=0;i<8;i++){
            float4 v; v.x=acc[i*4]; v.y=acc[i*4+1]; v.z=acc[i*4+2]; v.w=acc[i*4+3];
            *(float4*)(xo + i*4) = v;
        }
        #pragma unroll
        for (int d=0; d<32; d++){
            es = fmaf(acc[d], g2as[oc*32+d], es);
            ed = fmaf(acc[d], g2ad[oc*32+d], ed);
        }
    }
    es2[n] = es; ed2[n] = ed;
    den2[n] = __expf(lrelu2(es+ed));
}

// ---------------- K9: out = lrelu(x3@Wo1.T+bo1) @ Wo2.T + bo2 ----------------
__global__ __launch_bounds__(256) __attribute__((amdgpu_waves_per_eu(4,4))) void k_head(
    const float* __restrict__ x3, const float* __restrict__ Wo1, const float* __restrict__ bo1,
    const float* __restrict__ Wo2, const float* __restrict__ bo2,
    float* __restrict__ out, int N)
{
    int n = blockIdx.x*256 + threadIdx.x;
    if (n >= N) return;
    const float* xr = x3 + (size_t)n*128;
    float o0 = bo2[0], o1 = bo2[1];
    for (int oc=0; oc<4; oc++){
        float acc[32];
        #pragma unroll
        for (int o=0;o<32;o++) acc[o] = bo1[oc*32+o];
        for (int kc=0; kc<128; kc+=32){
            float xv[32];
            #pragma unroll
            for (int i=0;i<8;i++){
                float4 v = *(const float4*)(xr + kc + i*4);
                xv[i*4+0]=v.x; xv[i*4+1]=v.y; xv[i*4+2]=v.z; xv[i*4+3]=v.w;
            }
            #pragma unroll
            for (int o=0;o<32;o++){
                const float* wr = Wo1 + (size_t)(oc*32+o)*128 + kc;
                #pragma unroll
                for (int kk=0;kk<32;kk++) acc[o] = fmaf(xv[kk], wr[kk], acc[o]);
            }
        }
        #pragma unroll
        for (int o=0;o<32;o++){
            float v = lrelu01(acc[o]);
            o0 = fmaf(v, Wo2[oc*32+o],       o0);
            o1 = fmaf(v, Wo2[128 + oc*32+o], o1);
        }
    }
    out[(size_t)n*2+0] = o0;
    out[(size_t)n*2+1] = o1;
}

extern "C" void kernel_launch(void* const* d_in, const int* in_sizes, int n_in,
                              void* d_out, int out_size, void* d_ws, size_t ws_size,
                              hipStream_t stream)
{
    const float* des  = (const float*)d_in[0];
    const float* twt  = (const float*)d_in[1];
    const float* nump = (const float*)d_in[2];
    const float* catp = (const float*)d_in[3];
    const int*   ei   = (const int*)  d_in[4];
    const float* Wd = (const float*)d_in[5];   const float* bd = (const float*)d_in[6];
    const float* Wt = (const float*)d_in[7];   const float* bt = (const float*)d_in[8];
    const float* Wn = (const float*)d_in[9];   const float* bn = (const float*)d_in[10];
    const float* Wc = (const float*)d_in[11];  const float* bc = (const float*)d_in[12];
    const float* Wi = (const float*)d_in[13];  const float* bi = (const float*)d_in[14];
    const float* g1W  = (const float*)d_in[15];
    const float* g1as = (const float*)d_in[16];
    const float* g1ad = (const float*)d_in[17];
    const float* g1b  = (const float*)d_in[18];
    const float* g2W  = (const float*)d_in[19];
    const float* g2as = (const float*)d_in[20];
    const float* g2ad = (const float*)d_in[21];
    const float* g2b  = (const float*)d_in[22];
    const float* Wo1 = (const float*)d_in[23]; const float* bo1 = (const float*)d_in[24];
    const float* Wo2 = (const float*)d_in[25]; const float* bo2 = (const float*)d_in[26];
    float* out = (float*)d_out;

    const int N = in_sizes[0] / 768;
    const int E = in_sizes[4] / 2;

    float* b0   = (float*)d_ws;                 // x0 -> x2 -> x3
    float* b1   = b0   + (size_t)N*128;         // xw1 -> xw2
    float* es1  = b1   + (size_t)N*128;
    float* ed1  = es1  + (size_t)N*4;
    float* den1 = ed1  + (size_t)N*4;
    float* es2  = den1 + (size_t)N*4;
    float* ed2  = es2  + N;
    float* den2 = ed2  + N;
    int* counts = (int*)(den2 + N);
    int* excl   = counts + N;
    int* bsums  = excl   + N;
    int* indptr = bsums  + 256;
    int* cursor = indptr + (N+1);
    int* srcs   = cursor + N;

    const int gN256 = (N+255)/256;
    const int gE256 = (E+255)/256;
    const int gN128 = (N+127)/128;
    const int nb    = (N + SCAN_BS - 1)/SCAN_BS;

    hipLaunchKernelGGL(k_zero,   dim3(gN256), dim3(256), 0, stream, counts, N);
    hipLaunchKernelGGL(k_feat,   dim3(gN256), dim3(256), 0, stream,
                       des, Wd, bd, 0,  nump, catp, Wn, bn, Wc, bc, 1, b0, N);
    hipLaunchKernelGGL(k_feat,   dim3(gN256), dim3(256), 0, stream,
                       twt, Wt, bt, 32, nump, catp, Wn, bn, Wc, bc, 0, b0, N);
    hipLaunchKernelGGL(k_x1_xw1, dim3(gN128), dim3(512), 0, stream,
                       b0, Wi, bi, g1W, g1as, g1ad, b1, es1, ed1, den1, N);
    hipLaunchKernelGGL(k_hist,   dim3(gE256), dim3(256), 0, stream, ei, E, counts);
    hipLaunchKernelGGL(k_scan1,  dim3(nb),    dim3(256), 0, stream, counts, excl, bsums, N);
    hipLaunchKernelGGL(k_scan2,  dim3(1),     dim3(256), 0, stream, bsums, nb);
    hipLaunchKernelGGL(k_scan3,  dim3(gN256), dim3(256), 0, stream, excl, bsums, indptr, cursor, N, E);
    hipLaunchKernelGGL(k_scatter,dim3(gE256), dim3(256), 0, stream, ei, E, cursor, srcs);
    hipLaunchKernelGGL(k_den1,   dim3(gE256), dim3(256), 0, stream, ei, E, es1, ed1, den1);
    hipLaunchKernelGGL(k_agg1,   dim3(N),     dim3(128), 0, stream,
                       indptr, srcs, b1, es1, ed1, den1, g1b, b0);
    hipLaunchKernelGGL(k_xw2,    dim3(gN256), dim3(256), 0, stream,
                       b0, g2W, g2as, g2ad, b1, es2, ed2, den2, N);
    hipLaunchKernelGGL(k_den2,   dim3(gE256), dim3(256), 0, stream, ei, E, es2, ed2, den2);
    hipLaunchKernelGGL(k_agg2,   dim3(N),     dim3(128), 0, stream,
                       indptr, srcs, b1, es2, ed2, den2, g2b, b0);
    hipLaunchKernelGGL(k_head,   dim3(gN256), dim3(256), 0, stream,
                       b0, Wo1, bo1, Wo2, bo2, out, N);
}